// Round 5
// baseline (589.860 us; speedup 1.0000x reference)
//
#include <hip/hip_runtime.h>

#define NROWS 8192
#define DDIM  512
#define INV_TAU 14.285714285714286f

typedef short short8 __attribute__((ext_vector_type(8)));
typedef float f32x4 __attribute__((ext_vector_type(4)));

__device__ static inline float bf2f(unsigned short u) {
  return __uint_as_float(((unsigned int)u) << 16);
}
__device__ static inline unsigned short f2bf(float f) {
  unsigned int u = __float_as_uint(f);
  u += 0x7fffu + ((u >> 16) & 1u);   // round-to-nearest-even
  return (unsigned short)(u >> 16);
}

__device__ static inline void load_lds16(const void* g, void* l) {
  __builtin_amdgcn_global_load_lds(
      (const __attribute__((address_space(1))) void*)g,
      (__attribute__((address_space(3))) void*)l, 16, 0, 0);
}

// ---------------- normalize: fp32 rows -> bf16 normalized rows ----------------
__global__ __launch_bounds__(256) void norm_kernel(
    const float* __restrict__ zi, const float* __restrict__ zj,
    unsigned short* __restrict__ ziN, unsigned short* __restrict__ zjN) {
  int rid = blockIdx.x * 4 + (threadIdx.x >> 6);   // 0..16383
  int lane = threadIdx.x & 63;
  const float* src;
  unsigned short* dst;
  if (rid < NROWS) { src = zi + (size_t)rid * DDIM; dst = ziN + (size_t)rid * DDIM; }
  else             { src = zj + (size_t)(rid - NROWS) * DDIM; dst = zjN + (size_t)(rid - NROWS) * DDIM; }
  float4 v0 = *(const float4*)(src + lane * 4);
  float4 v1 = *(const float4*)(src + 256 + lane * 4);
  float ss = v0.x*v0.x + v0.y*v0.y + v0.z*v0.z + v0.w*v0.w
           + v1.x*v1.x + v1.y*v1.y + v1.z*v1.z + v1.w*v1.w;
  #pragma unroll
  for (int off = 1; off < 64; off <<= 1) ss += __shfl_xor(ss, off);
  float scale = 1.0f / fmaxf(sqrtf(ss), 1e-8f);
  ushort4 o0, o1;
  o0.x = f2bf(v0.x*scale); o0.y = f2bf(v0.y*scale); o0.z = f2bf(v0.z*scale); o0.w = f2bf(v0.w*scale);
  o1.x = f2bf(v1.x*scale); o1.y = f2bf(v1.y*scale); o1.z = f2bf(v1.z*scale); o1.w = f2bf(v1.w*scale);
  *(ushort4*)(dst + lane * 4) = o0;
  *(ushort4*)(dst + 256 + lane * 4) = o1;
}

// ---------------- zero row/col accumulators (contiguous 16384 floats) --------
__global__ __launch_bounds__(256) void zero_kernel(float* __restrict__ p) {
  p[blockIdx.x * 256 + threadIdx.x] = 0.0f;
}

// ---------------- pos[i] = dot(ziN[i], zjN[i]) / tau --------------------------
__global__ __launch_bounds__(256) void pos_kernel(
    const unsigned short* __restrict__ ziN, const unsigned short* __restrict__ zjN,
    float* __restrict__ pos) {
  int row = blockIdx.x * 4 + (threadIdx.x >> 6);
  int lane = threadIdx.x & 63;
  const unsigned short* a = ziN + (size_t)row * DDIM;
  const unsigned short* b = zjN + (size_t)row * DDIM;
  ushort4 a0 = *(const ushort4*)(a + lane * 4);
  ushort4 a1 = *(const ushort4*)(a + 256 + lane * 4);
  ushort4 b0 = *(const ushort4*)(b + lane * 4);
  ushort4 b1 = *(const ushort4*)(b + 256 + lane * 4);
  float s = bf2f(a0.x)*bf2f(b0.x) + bf2f(a0.y)*bf2f(b0.y)
          + bf2f(a0.z)*bf2f(b0.z) + bf2f(a0.w)*bf2f(b0.w)
          + bf2f(a1.x)*bf2f(b1.x) + bf2f(a1.y)*bf2f(b1.y)
          + bf2f(a1.z)*bf2f(b1.z) + bf2f(a1.w)*bf2f(b1.w);
  #pragma unroll
  for (int off = 1; off < 64; off <<= 1) s += __shfl_xor(s, off);
  if (lane == 0) pos[row] = s * INV_TAU;
}

// ---------------- fused sim GEMM + exp + row/col sum (R3 engine, ablatable) --
// MODE 0: full (real compute).  Probes (outputs corrupted, re-zeroed later):
// MODE 1: no MFMA.  MODE 2: no ds_read frags.  MODE 3: no staging/vmcnt.
// MODE 4: no in-loop barriers.
#define KEEP(x) asm volatile("" :: "v"(x))

template<int MODE>
__global__ __launch_bounds__(512, 2) void sim_kernel(
    const unsigned short* __restrict__ ziN, const unsigned short* __restrict__ zjN,
    float* __restrict__ row_sum, float* __restrict__ col_sum) {
  constexpr bool DO_MFMA  = (MODE != 1);
  constexpr bool DO_RD    = (MODE != 2);
  constexpr bool DO_STAGE = (MODE != 3);
  constexpr bool DO_BAR   = (MODE != 4);

  __shared__ unsigned short lds[65536];   // 128 KiB = 4 slots x 32KB
  const int tid  = threadIdx.x;
  const int lane = tid & 63;
  const int wid  = tid >> 6;
  const int wr   = wid >> 2;        // 0..1  (m-half: 128 rows of sub-tile)
  const int wc   = wid & 3;         // 0..3  (n-quarter: 64 cols)
  const int fr   = lane & 15;
  const int g    = lane >> 4;
  const int by   = blockIdx.y, bx = blockIdx.x;

  const int rowoff = wid * 16 + fr;       // 0..127
  const int koff   = g * 8;               // 0,8,16,24

  f32x4 acc[8][4] = {};
  short8 afrag[4], bfrag[4];

  if constexpr (!DO_RD) {
    // constant frags (cheap init; MFMAs run on these)
    #pragma unroll
    for (int m = 0; m < 4; ++m)
      #pragma unroll
      for (int e = 0; e < 8; ++e) { afrag[m][e] = (short)(fr + e); bfrag[m][e] = (short)(g + e); }
  }

  auto stage_half = [&](const unsigned short* __restrict__ base, int growbase,
                        int kt3, int dstoff) {
    load_lds16(base + (size_t)(growbase + rowoff) * DDIM + kt3 * 32 + koff,
               (char*)lds + dstoff + tid * 16);
  };

  const int ard = wr * 8192 + g * 256 + fr * 16;          // + slot + m*1024
  const int brd = 16384 + wc * 4096 + g * 256 + fr * 16;  // + slot + n*1024

  auto phase_pair = [&](int vk, bool doStage, int vm) {
    const int slot = (vk & 3) * 32768;
    int brow3 = 0, bcol3 = 0, kt3 = 0, slot3 = 0;
    if (doStage) {
      const int vk3 = vk + 3, s3 = vk3 >> 4;
      kt3   = vk3 & 15;
      brow3 = by * 512 + (s3 >> 1) * 256;
      bcol3 = bx * 512 + ((s3 & 1) ^ (s3 >> 1)) * 256;
      slot3 = (vk3 & 3) * 32768;
    }
    // ---------- phase 0
    if constexpr (DO_RD) {
      #pragma unroll
      for (int n = 0; n < 4; ++n)
        bfrag[n] = *(const short8*)((const char*)lds + slot + brd + n * 1024);
      #pragma unroll
      for (int m = 0; m < 4; ++m)
        afrag[m] = *(const short8*)((const char*)lds + slot + ard + m * 1024);
    }
    if constexpr (DO_STAGE) {
      if (doStage) {
        stage_half(ziN, brow3,       kt3, slot3);
        stage_half(ziN, brow3 + 128, kt3, slot3 + 8192);
      }
    }
    if constexpr (DO_BAR) __builtin_amdgcn_s_barrier();
    asm volatile("s_waitcnt lgkmcnt(0)" ::: "memory");
    __builtin_amdgcn_sched_barrier(0);
    if constexpr (DO_MFMA) {
      __builtin_amdgcn_s_setprio(1);
      #pragma unroll
      for (int m = 0; m < 4; ++m)
        #pragma unroll
        for (int n = 0; n < 4; ++n)
          acc[m][n] = __builtin_amdgcn_mfma_f32_16x16x32_bf16(
              afrag[m], bfrag[n], acc[m][n], 0, 0, 0);
      __builtin_amdgcn_s_setprio(0);
    } else {
      #pragma unroll
      for (int m = 0; m < 4; ++m) { KEEP(afrag[m]); KEEP(bfrag[m]); }
    }
    if constexpr (DO_BAR) __builtin_amdgcn_s_barrier();
    // ---------- phase 1
    if constexpr (DO_RD) {
      #pragma unroll
      for (int m = 0; m < 4; ++m)
        afrag[m] = *(const short8*)((const char*)lds + slot + ard + (m + 4) * 1024);
    }
    if constexpr (DO_STAGE) {
      if (doStage) {
        stage_half(zjN, bcol3,       kt3, slot3 + 16384);
        stage_half(zjN, bcol3 + 128, kt3, slot3 + 16384 + 8192);
      }
      if (vm == 8)      asm volatile("s_waitcnt vmcnt(8)" ::: "memory");
      else if (vm == 4) asm volatile("s_waitcnt vmcnt(4)" ::: "memory");
      else              asm volatile("s_waitcnt vmcnt(0)" ::: "memory");
    }
    if constexpr (DO_BAR) __builtin_amdgcn_s_barrier();
    asm volatile("s_waitcnt lgkmcnt(0)" ::: "memory");
    __builtin_amdgcn_sched_barrier(0);
    if constexpr (DO_MFMA) {
      __builtin_amdgcn_s_setprio(1);
      #pragma unroll
      for (int m = 0; m < 4; ++m)
        #pragma unroll
        for (int n = 0; n < 4; ++n)
          acc[m + 4][n] = __builtin_amdgcn_mfma_f32_16x16x32_bf16(
              afrag[m], bfrag[n], acc[m + 4][n], 0, 0, 0);
      __builtin_amdgcn_s_setprio(0);
    } else {
      #pragma unroll
      for (int m = 0; m < 4; ++m) KEEP(afrag[m]);
    }
    if constexpr (DO_BAR) __builtin_amdgcn_s_barrier();
  };

  const float Cc = INV_TAU * 1.4426950408889634f;
  auto epi = [&](int s) {
    const int brow_s = by * 512 + (s >> 1) * 256;
    const int bcol_s = bx * 512 + ((s & 1) ^ (s >> 1)) * 256;
    const int r0 = brow_s + wr * 128 + g * 4;   // + m*16 + r
    const int c0 = bcol_s + wc * 64 + fr;       // + n*16
    #pragma unroll
    for (int m = 0; m < 8; ++m)
      #pragma unroll
      for (int n = 0; n < 4; ++n)
        #pragma unroll
        for (int r = 0; r < 4; ++r) {
          int gi = r0 + m * 16 + r;
          int gj = c0 + n * 16;
          float e = exp2f((acc[m][n][r] - 1.0f) * Cc);
          acc[m][n][r] = (gi == gj) ? 0.0f : e;
        }
    #pragma unroll
    for (int n = 0; n < 4; ++n) {
      float cs = 0.0f;
      #pragma unroll
      for (int m = 0; m < 8; ++m)
        #pragma unroll
        for (int r = 0; r < 4; ++r) cs += acc[m][n][r];
      cs += __shfl_xor(cs, 16);
      cs += __shfl_xor(cs, 32);
      if (lane < 16) atomicAdd(&col_sum[c0 + n * 16], cs);
    }
    #pragma unroll
    for (int m = 0; m < 8; ++m)
      #pragma unroll
      for (int r = 0; r < 4; ++r) {
        float rs = acc[m][0][r] + acc[m][1][r] + acc[m][2][r] + acc[m][3][r];
        rs += __shfl_xor(rs, 1);
        rs += __shfl_xor(rs, 2);
        rs += __shfl_xor(rs, 4);
        rs += __shfl_xor(rs, 8);
        if (fr == 0) atomicAdd(&row_sum[r0 + m * 16 + r], rs);
      }
    #pragma unroll
    for (int m = 0; m < 8; ++m)
      #pragma unroll
      for (int n = 0; n < 4; ++n) acc[m][n] = (f32x4){0.f, 0.f, 0.f, 0.f};
  };

  // ---- prologue
  if constexpr (DO_STAGE) {
    #pragma unroll
    for (int v = 0; v < 3; ++v) {
      const int sl = v * 32768;
      stage_half(ziN, by * 512,       v, sl);
      stage_half(ziN, by * 512 + 128, v, sl + 8192);
      stage_half(zjN, bx * 512,       v, sl + 16384);
      stage_half(zjN, bx * 512 + 128, v, sl + 16384 + 8192);
    }
    asm volatile("s_waitcnt vmcnt(8)" ::: "memory");
  }
  __builtin_amdgcn_s_barrier();

  // ---- main virtual-K loop: 64 K-tiles across 4 sub-tiles
  #pragma unroll 4
  for (int vk = 0; vk < 60; ++vk) {
    phase_pair(vk, true, 8);
    if ((vk & 15) == 15) epi(vk >> 4);
  }
  phase_pair(60, true, 8);
  phase_pair(61, false, 4);
  phase_pair(62, false, 0);
  phase_pair(63, false, 0);
  epi(3);
}

// ---------------- finalize: 3 scalars ----------------------------------------
__global__ __launch_bounds__(256) void finalize_kernel(
    const float* __restrict__ row_sum, const float* __restrict__ col_sum,
    const float* __restrict__ pos, float* __restrict__ out) {
  __shared__ float sA[4], sB[4];
  float sa = 0.0f, sb = 0.0f;
  for (int i = threadIdx.x; i < NROWS; i += 256) {
    float p = pos[i];
    sa += (INV_TAU + __logf(row_sum[i])) - p;
    sb += (INV_TAU + __logf(col_sum[i])) - p;
  }
  #pragma unroll
  for (int off = 1; off < 64; off <<= 1) {
    sa += __shfl_xor(sa, off);
    sb += __shfl_xor(sb, off);
  }
  if ((threadIdx.x & 63) == 0) { sA[threadIdx.x >> 6] = sa; sB[threadIdx.x >> 6] = sb; }
  __syncthreads();
  if (threadIdx.x == 0) {
    float ta = sA[0] + sA[1] + sA[2] + sA[3];
    float tb = sB[0] + sB[1] + sB[2] + sB[3];
    float e2t = ta / (float)NROWS;
    float t2e = tb / (float)NROWS;
    out[0] = 0.5f * (e2t + t2e);
    out[1] = e2t;
    out[2] = t2e;
  }
}

extern "C" void kernel_launch(void* const* d_in, const int* in_sizes, int n_in,
                              void* d_out, int out_size, void* d_ws, size_t ws_size,
                              hipStream_t stream) {
  const float* z_i = (const float*)d_in[0];
  const float* z_j = (const float*)d_in[1];
  float* out = (float*)d_out;
  char* ws = (char*)d_ws;
  unsigned short* ziN = (unsigned short*)ws;                       // 8 MB
  unsigned short* zjN = (unsigned short*)(ws + 8388608);           // 8 MB
  float* row_sum = (float*)(ws + 16777216);                        // 32 KB
  float* col_sum = row_sum + NROWS;                                // 32 KB (contiguous)
  float* pos     = col_sum + NROWS;                                // 32 KB

  dim3 grid(16, 16);

  norm_kernel<<<4096, 256, 0, stream>>>(z_i, z_j, ziN, zjN);

  // ---- ablation probes (corrupt row/col sums; re-zeroed below) ----
  sim_kernel<1><<<grid, 512, 0, stream>>>(ziN, zjN, row_sum, col_sum); // noMFMA
  sim_kernel<2><<<grid, 512, 0, stream>>>(ziN, zjN, row_sum, col_sum); // noRD
  sim_kernel<3><<<grid, 512, 0, stream>>>(ziN, zjN, row_sum, col_sum); // noStage
  sim_kernel<4><<<grid, 512, 0, stream>>>(ziN, zjN, row_sum, col_sum); // noBar

  // ---- real compute ----
  zero_kernel<<<64, 256, 0, stream>>>(row_sum);                    // zeros row+col (contiguous)
  pos_kernel<<<2048, 256, 0, stream>>>(ziN, zjN, pos);
  sim_kernel<0><<<grid, 512, 0, stream>>>(ziN, zjN, row_sum, col_sum);
  finalize_kernel<<<1, 256, 0, stream>>>(row_sum, col_sum, pos, out);
}

// Round 6
// 588.971 us; speedup vs baseline: 1.0015x; 1.0015x over previous
//
#include <hip/hip_runtime.h>

#define NROWS 8192
#define DDIM  512
#define INV_TAU 14.285714285714286f

typedef short short8 __attribute__((ext_vector_type(8)));
typedef float f32x4 __attribute__((ext_vector_type(4)));

__device__ static inline float bf2f(unsigned short u) {
  return __uint_as_float(((unsigned int)u) << 16);
}
__device__ static inline unsigned short f2bf(float f) {
  unsigned int u = __float_as_uint(f);
  u += 0x7fffu + ((u >> 16) & 1u);   // round-to-nearest-even
  return (unsigned short)(u >> 16);
}

__device__ static inline void load_lds16(const void* g, void* l) {
  __builtin_amdgcn_global_load_lds(
      (const __attribute__((address_space(1))) void*)g,
      (__attribute__((address_space(3))) void*)l, 16, 0, 0);
}

// ---------------- normalize: fp32 rows -> bf16 normalized rows ----------------
__global__ __launch_bounds__(256) void norm_kernel(
    const float* __restrict__ zi, const float* __restrict__ zj,
    unsigned short* __restrict__ ziN, unsigned short* __restrict__ zjN) {
  int rid = blockIdx.x * 4 + (threadIdx.x >> 6);   // 0..16383
  int lane = threadIdx.x & 63;
  const float* src;
  unsigned short* dst;
  if (rid < NROWS) { src = zi + (size_t)rid * DDIM; dst = ziN + (size_t)rid * DDIM; }
  else             { src = zj + (size_t)(rid - NROWS) * DDIM; dst = zjN + (size_t)(rid - NROWS) * DDIM; }
  float4 v0 = *(const float4*)(src + lane * 4);
  float4 v1 = *(const float4*)(src + 256 + lane * 4);
  float ss = v0.x*v0.x + v0.y*v0.y + v0.z*v0.z + v0.w*v0.w
           + v1.x*v1.x + v1.y*v1.y + v1.z*v1.z + v1.w*v1.w;
  #pragma unroll
  for (int off = 1; off < 64; off <<= 1) ss += __shfl_xor(ss, off);
  float scale = 1.0f / fmaxf(sqrtf(ss), 1e-8f);
  ushort4 o0, o1;
  o0.x = f2bf(v0.x*scale); o0.y = f2bf(v0.y*scale); o0.z = f2bf(v0.z*scale); o0.w = f2bf(v0.w*scale);
  o1.x = f2bf(v1.x*scale); o1.y = f2bf(v1.y*scale); o1.z = f2bf(v1.z*scale); o1.w = f2bf(v1.w*scale);
  *(ushort4*)(dst + lane * 4) = o0;
  *(ushort4*)(dst + 256 + lane * 4) = o1;
}

// ---------------- zero row/col accumulators (contiguous 16384 floats) --------
__global__ __launch_bounds__(256) void zero_kernel(float* __restrict__ p) {
  p[blockIdx.x * 256 + threadIdx.x] = 0.0f;
}

// ---------------- pos[i] = dot(ziN[i], zjN[i]) / tau --------------------------
__global__ __launch_bounds__(256) void pos_kernel(
    const unsigned short* __restrict__ ziN, const unsigned short* __restrict__ zjN,
    float* __restrict__ pos) {
  int row = blockIdx.x * 4 + (threadIdx.x >> 6);
  int lane = threadIdx.x & 63;
  const unsigned short* a = ziN + (size_t)row * DDIM;
  const unsigned short* b = zjN + (size_t)row * DDIM;
  ushort4 a0 = *(const ushort4*)(a + lane * 4);
  ushort4 a1 = *(const ushort4*)(a + 256 + lane * 4);
  ushort4 b0 = *(const ushort4*)(b + lane * 4);
  ushort4 b1 = *(const ushort4*)(b + 256 + lane * 4);
  float s = bf2f(a0.x)*bf2f(b0.x) + bf2f(a0.y)*bf2f(b0.y)
          + bf2f(a0.z)*bf2f(b0.z) + bf2f(a0.w)*bf2f(b0.w)
          + bf2f(a1.x)*bf2f(b1.x) + bf2f(a1.y)*bf2f(b1.y)
          + bf2f(a1.z)*bf2f(b1.z) + bf2f(a1.w)*bf2f(b1.w);
  #pragma unroll
  for (int off = 1; off < 64; off <<= 1) s += __shfl_xor(s, off);
  if (lane == 0) pos[row] = s * INV_TAU;
}

// ---------------- fused sim GEMM + exp + row/col sum (R3 engine, ablatable) --
// Body shared by 5 distinctly-NAMED kernels so rocprof attributes each mode.
// MODE 0: full.  1: no MFMA.  2: no ds_read frags.  3: no staging/vmcnt.
// MODE 4: no in-loop barriers.
#define KEEP(x) asm volatile("" :: "v"(x))

template<int MODE>
__device__ __attribute__((always_inline)) void sim_body(
    const unsigned short* __restrict__ ziN, const unsigned short* __restrict__ zjN,
    float* __restrict__ row_sum, float* __restrict__ col_sum) {
  constexpr bool DO_MFMA  = (MODE != 1);
  constexpr bool DO_RD    = (MODE != 2);
  constexpr bool DO_STAGE = (MODE != 3);
  constexpr bool DO_BAR   = (MODE != 4);

  __shared__ unsigned short lds[65536];   // 128 KiB = 4 slots x 32KB
  const int tid  = threadIdx.x;
  const int lane = tid & 63;
  const int wid  = tid >> 6;
  const int wr   = wid >> 2;        // 0..1  (m-half: 128 rows of sub-tile)
  const int wc   = wid & 3;         // 0..3  (n-quarter: 64 cols)
  const int fr   = lane & 15;
  const int g    = lane >> 4;
  const int by   = blockIdx.y, bx = blockIdx.x;

  const int rowoff = wid * 16 + fr;       // 0..127
  const int koff   = g * 8;               // 0,8,16,24

  f32x4 acc[8][4] = {};
  short8 afrag[4], bfrag[4];

  if constexpr (!DO_RD) {
    #pragma unroll
    for (int m = 0; m < 4; ++m)
      #pragma unroll
      for (int e = 0; e < 8; ++e) { afrag[m][e] = (short)(fr + e); bfrag[m][e] = (short)(g + e); }
  }

  auto stage_half = [&](const unsigned short* __restrict__ base, int growbase,
                        int kt3, int dstoff) {
    load_lds16(base + (size_t)(growbase + rowoff) * DDIM + kt3 * 32 + koff,
               (char*)lds + dstoff + tid * 16);
  };

  const int ard = wr * 8192 + g * 256 + fr * 16;          // + slot + m*1024
  const int brd = 16384 + wc * 4096 + g * 256 + fr * 16;  // + slot + n*1024

  auto phase_pair = [&](int vk, bool doStage, int vm) {
    const int slot = (vk & 3) * 32768;
    int brow3 = 0, bcol3 = 0, kt3 = 0, slot3 = 0;
    if (doStage) {
      const int vk3 = vk + 3, s3 = vk3 >> 4;
      kt3   = vk3 & 15;
      brow3 = by * 512 + (s3 >> 1) * 256;
      bcol3 = bx * 512 + ((s3 & 1) ^ (s3 >> 1)) * 256;
      slot3 = (vk3 & 3) * 32768;
    }
    // ---------- phase 0
    if constexpr (DO_RD) {
      #pragma unroll
      for (int n = 0; n < 4; ++n)
        bfrag[n] = *(const short8*)((const char*)lds + slot + brd + n * 1024);
      #pragma unroll
      for (int m = 0; m < 4; ++m)
        afrag[m] = *(const short8*)((const char*)lds + slot + ard + m * 1024);
    }
    if constexpr (DO_STAGE) {
      if (doStage) {
        stage_half(ziN, brow3,       kt3, slot3);
        stage_half(ziN, brow3 + 128, kt3, slot3 + 8192);
      }
    }
    if constexpr (DO_BAR) __builtin_amdgcn_s_barrier();
    asm volatile("s_waitcnt lgkmcnt(0)" ::: "memory");
    __builtin_amdgcn_sched_barrier(0);
    if constexpr (DO_MFMA) {
      __builtin_amdgcn_s_setprio(1);
      #pragma unroll
      for (int m = 0; m < 4; ++m)
        #pragma unroll
        for (int n = 0; n < 4; ++n)
          acc[m][n] = __builtin_amdgcn_mfma_f32_16x16x32_bf16(
              afrag[m], bfrag[n], acc[m][n], 0, 0, 0);
      __builtin_amdgcn_s_setprio(0);
    } else {
      #pragma unroll
      for (int m = 0; m < 4; ++m) { KEEP(afrag[m]); KEEP(bfrag[m]); }
    }
    if constexpr (DO_BAR) __builtin_amdgcn_s_barrier();
    // ---------- phase 1
    if constexpr (DO_RD) {
      #pragma unroll
      for (int m = 0; m < 4; ++m)
        afrag[m] = *(const short8*)((const char*)lds + slot + ard + (m + 4) * 1024);
    }
    if constexpr (DO_STAGE) {
      if (doStage) {
        stage_half(zjN, bcol3,       kt3, slot3 + 16384);
        stage_half(zjN, bcol3 + 128, kt3, slot3 + 16384 + 8192);
      }
      if (vm == 8)      asm volatile("s_waitcnt vmcnt(8)" ::: "memory");
      else if (vm == 4) asm volatile("s_waitcnt vmcnt(4)" ::: "memory");
      else              asm volatile("s_waitcnt vmcnt(0)" ::: "memory");
    }
    if constexpr (DO_BAR) __builtin_amdgcn_s_barrier();
    asm volatile("s_waitcnt lgkmcnt(0)" ::: "memory");
    __builtin_amdgcn_sched_barrier(0);
    if constexpr (DO_MFMA) {
      __builtin_amdgcn_s_setprio(1);
      #pragma unroll
      for (int m = 0; m < 4; ++m)
        #pragma unroll
        for (int n = 0; n < 4; ++n)
          acc[m + 4][n] = __builtin_amdgcn_mfma_f32_16x16x32_bf16(
              afrag[m], bfrag[n], acc[m + 4][n], 0, 0, 0);
      __builtin_amdgcn_s_setprio(0);
    } else {
      #pragma unroll
      for (int m = 0; m < 4; ++m) KEEP(afrag[m]);
    }
    if constexpr (DO_BAR) __builtin_amdgcn_s_barrier();
  };

  const float Cc = INV_TAU * 1.4426950408889634f;
  auto epi = [&](int s) {
    const int brow_s = by * 512 + (s >> 1) * 256;
    const int bcol_s = bx * 512 + ((s & 1) ^ (s >> 1)) * 256;
    const int r0 = brow_s + wr * 128 + g * 4;   // + m*16 + r
    const int c0 = bcol_s + wc * 64 + fr;       // + n*16
    #pragma unroll
    for (int m = 0; m < 8; ++m)
      #pragma unroll
      for (int n = 0; n < 4; ++n)
        #pragma unroll
        for (int r = 0; r < 4; ++r) {
          int gi = r0 + m * 16 + r;
          int gj = c0 + n * 16;
          float e = exp2f((acc[m][n][r] - 1.0f) * Cc);
          acc[m][n][r] = (gi == gj) ? 0.0f : e;
        }
    #pragma unroll
    for (int n = 0; n < 4; ++n) {
      float cs = 0.0f;
      #pragma unroll
      for (int m = 0; m < 8; ++m)
        #pragma unroll
        for (int r = 0; r < 4; ++r) cs += acc[m][n][r];
      cs += __shfl_xor(cs, 16);
      cs += __shfl_xor(cs, 32);
      if (lane < 16) atomicAdd(&col_sum[c0 + n * 16], cs);
    }
    #pragma unroll
    for (int m = 0; m < 8; ++m)
      #pragma unroll
      for (int r = 0; r < 4; ++r) {
        float rs = acc[m][0][r] + acc[m][1][r] + acc[m][2][r] + acc[m][3][r];
        rs += __shfl_xor(rs, 1);
        rs += __shfl_xor(rs, 2);
        rs += __shfl_xor(rs, 4);
        rs += __shfl_xor(rs, 8);
        if (fr == 0) atomicAdd(&row_sum[r0 + m * 16 + r], rs);
      }
    #pragma unroll
    for (int m = 0; m < 8; ++m)
      #pragma unroll
      for (int n = 0; n < 4; ++n) acc[m][n] = (f32x4){0.f, 0.f, 0.f, 0.f};
  };

  // ---- prologue
  if constexpr (DO_STAGE) {
    #pragma unroll
    for (int v = 0; v < 3; ++v) {
      const int sl = v * 32768;
      stage_half(ziN, by * 512,       v, sl);
      stage_half(ziN, by * 512 + 128, v, sl + 8192);
      stage_half(zjN, bx * 512,       v, sl + 16384);
      stage_half(zjN, bx * 512 + 128, v, sl + 16384 + 8192);
    }
    asm volatile("s_waitcnt vmcnt(8)" ::: "memory");
  }
  __builtin_amdgcn_s_barrier();

  // ---- main virtual-K loop: 64 K-tiles across 4 sub-tiles
  #pragma unroll 4
  for (int vk = 0; vk < 60; ++vk) {
    phase_pair(vk, true, 8);
    if ((vk & 15) == 15) epi(vk >> 4);
  }
  phase_pair(60, true, 8);
  phase_pair(61, false, 4);
  phase_pair(62, false, 0);
  phase_pair(63, false, 0);
  epi(3);
}

// Distinctly-named kernels (rocprof attribution).
__global__ __launch_bounds__(512, 2) void sim_full(
    const unsigned short* __restrict__ a, const unsigned short* __restrict__ b,
    float* __restrict__ rs, float* __restrict__ cs) { sim_body<0>(a, b, rs, cs); }
__global__ __launch_bounds__(512, 2) void sim_noMFMA(
    const unsigned short* __restrict__ a, const unsigned short* __restrict__ b,
    float* __restrict__ rs, float* __restrict__ cs) { sim_body<1>(a, b, rs, cs); }
__global__ __launch_bounds__(512, 2) void sim_noRD(
    const unsigned short* __restrict__ a, const unsigned short* __restrict__ b,
    float* __restrict__ rs, float* __restrict__ cs) { sim_body<2>(a, b, rs, cs); }
__global__ __launch_bounds__(512, 2) void sim_noStage(
    const unsigned short* __restrict__ a, const unsigned short* __restrict__ b,
    float* __restrict__ rs, float* __restrict__ cs) { sim_body<3>(a, b, rs, cs); }
__global__ __launch_bounds__(512, 2) void sim_noBar(
    const unsigned short* __restrict__ a, const unsigned short* __restrict__ b,
    float* __restrict__ rs, float* __restrict__ cs) { sim_body<4>(a, b, rs, cs); }

// ---------------- finalize: 3 scalars ----------------------------------------
__global__ __launch_bounds__(256) void finalize_kernel(
    const float* __restrict__ row_sum, const float* __restrict__ col_sum,
    const float* __restrict__ pos, float* __restrict__ out) {
  __shared__ float sA[4], sB[4];
  float sa = 0.0f, sb = 0.0f;
  for (int i = threadIdx.x; i < NROWS; i += 256) {
    float p = pos[i];
    sa += (INV_TAU + __logf(row_sum[i])) - p;
    sb += (INV_TAU + __logf(col_sum[i])) - p;
  }
  #pragma unroll
  for (int off = 1; off < 64; off <<= 1) {
    sa += __shfl_xor(sa, off);
    sb += __shfl_xor(sb, off);
  }
  if ((threadIdx.x & 63) == 0) { sA[threadIdx.x >> 6] = sa; sB[threadIdx.x >> 6] = sb; }
  __syncthreads();
  if (threadIdx.x == 0) {
    float ta = sA[0] + sA[1] + sA[2] + sA[3];
    float tb = sB[0] + sB[1] + sB[2] + sB[3];
    float e2t = ta / (float)NROWS;
    float t2e = tb / (float)NROWS;
    out[0] = 0.5f * (e2t + t2e);
    out[1] = e2t;
    out[2] = t2e;
  }
}

extern "C" void kernel_launch(void* const* d_in, const int* in_sizes, int n_in,
                              void* d_out, int out_size, void* d_ws, size_t ws_size,
                              hipStream_t stream) {
  const float* z_i = (const float*)d_in[0];
  const float* z_j = (const float*)d_in[1];
  float* out = (float*)d_out;
  char* ws = (char*)d_ws;
  unsigned short* ziN = (unsigned short*)ws;                       // 8 MB
  unsigned short* zjN = (unsigned short*)(ws + 8388608);           // 8 MB
  float* row_sum = (float*)(ws + 16777216);                        // 32 KB
  float* col_sum = row_sum + NROWS;                                // 32 KB (contiguous)
  float* pos     = col_sum + NROWS;                                // 32 KB

  dim3 grid(16, 16);

  norm_kernel<<<4096, 256, 0, stream>>>(z_i, z_j, ziN, zjN);

  // ---- ablation probes (corrupt row/col sums; re-zeroed below) ----
  sim_noMFMA <<<grid, 512, 0, stream>>>(ziN, zjN, row_sum, col_sum);
  sim_noRD   <<<grid, 512, 0, stream>>>(ziN, zjN, row_sum, col_sum);
  sim_noStage<<<grid, 512, 0, stream>>>(ziN, zjN, row_sum, col_sum);
  sim_noBar  <<<grid, 512, 0, stream>>>(ziN, zjN, row_sum, col_sum);

  // ---- real compute ----
  zero_kernel<<<64, 256, 0, stream>>>(row_sum);                    // zeros row+col (contiguous)
  pos_kernel<<<2048, 256, 0, stream>>>(ziN, zjN, pos);
  sim_full<<<grid, 512, 0, stream>>>(ziN, zjN, row_sum, col_sum);
  finalize_kernel<<<1, 256, 0, stream>>>(row_sum, col_sum, pos, out);
}

// Round 7
// 186.026 us; speedup vs baseline: 3.1708x; 3.1661x over previous
//
#include <hip/hip_runtime.h>

#define NROWS 8192
#define DDIM  512
#define INV_TAU 14.285714285714286f

typedef short short8 __attribute__((ext_vector_type(8)));
typedef float f32x4 __attribute__((ext_vector_type(4)));

__device__ static inline float bf2f(unsigned short u) {
  return __uint_as_float(((unsigned int)u) << 16);
}
__device__ static inline unsigned short f2bf(float f) {
  unsigned int u = __float_as_uint(f);
  u += 0x7fffu + ((u >> 16) & 1u);   // round-to-nearest-even
  return (unsigned short)(u >> 16);
}

__device__ static inline void load_lds16(const void* g, void* l) {
  __builtin_amdgcn_global_load_lds(
      (const __attribute__((address_space(1))) void*)g,
      (__attribute__((address_space(3))) void*)l, 16, 0, 0);
}

// ---------------- normalize: fp32 rows -> bf16 normalized rows ----------------
__global__ __launch_bounds__(256) void norm_kernel(
    const float* __restrict__ zi, const float* __restrict__ zj,
    unsigned short* __restrict__ ziN, unsigned short* __restrict__ zjN) {
  int rid = blockIdx.x * 4 + (threadIdx.x >> 6);   // 0..16383
  int lane = threadIdx.x & 63;
  const float* src;
  unsigned short* dst;
  if (rid < NROWS) { src = zi + (size_t)rid * DDIM; dst = ziN + (size_t)rid * DDIM; }
  else             { src = zj + (size_t)(rid - NROWS) * DDIM; dst = zjN + (size_t)(rid - NROWS) * DDIM; }
  float4 v0 = *(const float4*)(src + lane * 4);
  float4 v1 = *(const float4*)(src + 256 + lane * 4);
  float ss = v0.x*v0.x + v0.y*v0.y + v0.z*v0.z + v0.w*v0.w
           + v1.x*v1.x + v1.y*v1.y + v1.z*v1.z + v1.w*v1.w;
  #pragma unroll
  for (int off = 1; off < 64; off <<= 1) ss += __shfl_xor(ss, off);
  float scale = 1.0f / fmaxf(sqrtf(ss), 1e-8f);
  ushort4 o0, o1;
  o0.x = f2bf(v0.x*scale); o0.y = f2bf(v0.y*scale); o0.z = f2bf(v0.z*scale); o0.w = f2bf(v0.w*scale);
  o1.x = f2bf(v1.x*scale); o1.y = f2bf(v1.y*scale); o1.z = f2bf(v1.z*scale); o1.w = f2bf(v1.w*scale);
  *(ushort4*)(dst + lane * 4) = o0;
  *(ushort4*)(dst + 256 + lane * 4) = o1;
}

// ---------------- zero row/col accumulators (contiguous 16384 floats) --------
__global__ __launch_bounds__(256) void zero_kernel(float* __restrict__ p) {
  p[blockIdx.x * 256 + threadIdx.x] = 0.0f;
}

// ---------------- pos[i] = dot(ziN[i], zjN[i]) / tau --------------------------
__global__ __launch_bounds__(256) void pos_kernel(
    const unsigned short* __restrict__ ziN, const unsigned short* __restrict__ zjN,
    float* __restrict__ pos) {
  int row = blockIdx.x * 4 + (threadIdx.x >> 6);
  int lane = threadIdx.x & 63;
  const unsigned short* a = ziN + (size_t)row * DDIM;
  const unsigned short* b = zjN + (size_t)row * DDIM;
  ushort4 a0 = *(const ushort4*)(a + lane * 4);
  ushort4 a1 = *(const ushort4*)(a + 256 + lane * 4);
  ushort4 b0 = *(const ushort4*)(b + lane * 4);
  ushort4 b1 = *(const ushort4*)(b + 256 + lane * 4);
  float s = bf2f(a0.x)*bf2f(b0.x) + bf2f(a0.y)*bf2f(b0.y)
          + bf2f(a0.z)*bf2f(b0.z) + bf2f(a0.w)*bf2f(b0.w)
          + bf2f(a1.x)*bf2f(b1.x) + bf2f(a1.y)*bf2f(b1.y)
          + bf2f(a1.z)*bf2f(b1.z) + bf2f(a1.w)*bf2f(b1.w);
  #pragma unroll
  for (int off = 1; off < 64; off <<= 1) s += __shfl_xor(s, off);
  if (lane == 0) pos[row] = s * INV_TAU;
}

// ---------------- fused sim GEMM + exp + row/col sum (TLP / m97-replica) ------
// 128x128 tile, BK=64, 4 waves (2x2, 64x64 each), single-buffer LDS 32KB,
// plain __syncthreads 2-barrier loop (compiler-managed waits).
// LDS linear [128 rows][64 k]; both-sides chunk-XOR: chunk^(row&7) on the
// global SOURCE (gload_lds dest linear) and on frag ds_reads -> 2-way alias
// only (free, m136).  PAD>0 variant = occupancy probe (2 blocks/CU).
template<int PAD>
__device__ __forceinline__ void sim_tlp_body(
    const unsigned short* __restrict__ ziN, const unsigned short* __restrict__ zjN,
    float* __restrict__ row_sum, float* __restrict__ col_sum) {
  __shared__ unsigned short As[8192];   // 16 KB
  __shared__ unsigned short Bs[8192];   // 16 KB
  __shared__ char padv[PAD];
  if ((unsigned long long)row_sum == 1ull) ((volatile char*)padv)[0] = 1;

  const int tid  = threadIdx.x;
  const int lane = tid & 63;
  const int wid  = tid >> 6;
  const int wr   = wid >> 1, wc = wid & 1;   // 2x2 waves, 64x64 each
  const int fr   = lane & 15;
  const int g    = lane >> 4;
  const int brow = blockIdx.y * 128;
  const int bcol = blockIdx.x * 128;

  f32x4 acc[4][4] = {};

  #pragma unroll 1
  for (int kt = 0; kt < 8; ++kt) {
    if (kt) __syncthreads();     // WAR: prior reads done before overwrite
    #pragma unroll
    for (int q = 0; q < 4; ++q) {
      int idx = q * 256 + tid;
      int row = idx >> 3;
      int c   = idx & 7;
      load_lds16(ziN + (size_t)(brow + row) * DDIM + kt * 64 + ((c ^ (row & 7)) * 8),
                 (char*)As + idx * 16);
    }
    #pragma unroll
    for (int q = 0; q < 4; ++q) {
      int idx = q * 256 + tid;
      int row = idx >> 3;
      int c   = idx & 7;
      load_lds16(zjN + (size_t)(bcol + row) * DDIM + kt * 64 + ((c ^ (row & 7)) * 8),
                 (char*)Bs + idx * 16);
    }
    __syncthreads();             // RAW: staged data visible (vmcnt drain)
    #pragma unroll
    for (int kk = 0; kk < 2; ++kk) {
      short8 a[4], b[4];
      #pragma unroll
      for (int m = 0; m < 4; ++m) {
        int row = wr * 64 + m * 16 + fr;
        a[m] = *(const short8*)((const char*)As + row * 128 + (((kk * 4 + g) ^ (row & 7)) * 16));
      }
      #pragma unroll
      for (int n = 0; n < 4; ++n) {
        int row = wc * 64 + n * 16 + fr;
        b[n] = *(const short8*)((const char*)Bs + row * 128 + (((kk * 4 + g) ^ (row & 7)) * 16));
      }
      #pragma unroll
      for (int m = 0; m < 4; ++m)
        #pragma unroll
        for (int n = 0; n < 4; ++n)
          acc[m][n] = __builtin_amdgcn_mfma_f32_16x16x32_bf16(a[m], b[n], acc[m][n], 0, 0, 0);
    }
  }

  // epilogue: e = exp2((dot-1)*C), diag -> 0, row/col partial sums + atomics
  const float Cc = INV_TAU * 1.4426950408889634f;
  const int r0 = brow + wr * 64 + g * 4;   // + m*16 + r
  const int c0 = bcol + wc * 64 + fr;      // + n*16
  #pragma unroll
  for (int m = 0; m < 4; ++m)
    #pragma unroll
    for (int n = 0; n < 4; ++n)
      #pragma unroll
      for (int r = 0; r < 4; ++r) {
        int gi = r0 + m * 16 + r;
        int gj = c0 + n * 16;
        float e = exp2f((acc[m][n][r] - 1.0f) * Cc);
        acc[m][n][r] = (gi == gj) ? 0.0f : e;
      }
  #pragma unroll
  for (int n = 0; n < 4; ++n) {
    float cs = 0.0f;
    #pragma unroll
    for (int m = 0; m < 4; ++m)
      #pragma unroll
      for (int r = 0; r < 4; ++r) cs += acc[m][n][r];
    cs += __shfl_xor(cs, 16);
    cs += __shfl_xor(cs, 32);
    if (lane < 16) atomicAdd(&col_sum[c0 + n * 16], cs);
  }
  #pragma unroll
  for (int m = 0; m < 4; ++m)
    #pragma unroll
    for (int r = 0; r < 4; ++r) {
      float rs = acc[m][0][r] + acc[m][1][r] + acc[m][2][r] + acc[m][3][r];
      rs += __shfl_xor(rs, 1);
      rs += __shfl_xor(rs, 2);
      rs += __shfl_xor(rs, 4);
      rs += __shfl_xor(rs, 8);
      if (fr == 0) atomicAdd(&row_sum[r0 + m * 16 + r], rs);
    }
}

__global__ __launch_bounds__(256, 4) void sim_tlp(
    const unsigned short* __restrict__ a, const unsigned short* __restrict__ b,
    float* __restrict__ rs, float* __restrict__ cs) {
  sim_tlp_body<4>(a, b, rs, cs);            // 32 KB LDS -> 4 blocks/CU
}
__global__ __launch_bounds__(256, 4) void sim_tlpLow(
    const unsigned short* __restrict__ a, const unsigned short* __restrict__ b,
    float* __restrict__ rs, float* __restrict__ cs) {
  sim_tlp_body<36864>(a, b, rs, cs);        // 68 KB LDS -> 2 blocks/CU
}

// ---------------- finalize: 3 scalars ----------------------------------------
__global__ __launch_bounds__(256) void finalize_kernel(
    const float* __restrict__ row_sum, const float* __restrict__ col_sum,
    const float* __restrict__ pos, float* __restrict__ out) {
  __shared__ float sA[4], sB[4];
  float sa = 0.0f, sb = 0.0f;
  for (int i = threadIdx.x; i < NROWS; i += 256) {
    float p = pos[i];
    sa += (INV_TAU + __logf(row_sum[i])) - p;
    sb += (INV_TAU + __logf(col_sum[i])) - p;
  }
  #pragma unroll
  for (int off = 1; off < 64; off <<= 1) {
    sa += __shfl_xor(sa, off);
    sb += __shfl_xor(sb, off);
  }
  if ((threadIdx.x & 63) == 0) { sA[threadIdx.x >> 6] = sa; sB[threadIdx.x >> 6] = sb; }
  __syncthreads();
  if (threadIdx.x == 0) {
    float ta = sA[0] + sA[1] + sA[2] + sA[3];
    float tb = sB[0] + sB[1] + sB[2] + sB[3];
    float e2t = ta / (float)NROWS;
    float t2e = tb / (float)NROWS;
    out[0] = 0.5f * (e2t + t2e);
    out[1] = e2t;
    out[2] = t2e;
  }
}

extern "C" void kernel_launch(void* const* d_in, const int* in_sizes, int n_in,
                              void* d_out, int out_size, void* d_ws, size_t ws_size,
                              hipStream_t stream) {
  const float* z_i = (const float*)d_in[0];
  const float* z_j = (const float*)d_in[1];
  float* out = (float*)d_out;
  char* ws = (char*)d_ws;
  unsigned short* ziN = (unsigned short*)ws;                       // 8 MB
  unsigned short* zjN = (unsigned short*)(ws + 8388608);           // 8 MB
  float* row_sum = (float*)(ws + 16777216);                        // 32 KB
  float* col_sum = row_sum + NROWS;                                // 32 KB (contiguous)
  float* pos     = col_sum + NROWS;                                // 32 KB

  norm_kernel<<<4096, 256, 0, stream>>>(z_i, z_j, ziN, zjN);

  // occupancy probe: identical body, 2 blocks/CU, quarter grid.
  // Corrupts row/col sums; re-zeroed below.
  dim3 gprobe(64, 16);
  sim_tlpLow<<<gprobe, 256, 0, stream>>>(ziN, zjN, row_sum, col_sum);

  zero_kernel<<<64, 256, 0, stream>>>(row_sum);                    // zeros row+col (contiguous)
  pos_kernel<<<2048, 256, 0, stream>>>(ziN, zjN, pos);
  dim3 grid(64, 64);
  sim_tlp<<<grid, 256, 0, stream>>>(ziN, zjN, row_sum, col_sum);
  finalize_kernel<<<1, 256, 0, stream>>>(row_sum, col_sum, pos, out);
}

// Round 8
// 144.954 us; speedup vs baseline: 4.0693x; 1.2833x over previous
//
#include <hip/hip_runtime.h>
#include <hip/hip_fp8.h>

#define NROWS 8192
#define DDIM  512
#define INV_TAU 14.285714285714286f

typedef float f32x4 __attribute__((ext_vector_type(4)));

__device__ static inline unsigned char f2e4(float f) {
  __hip_fp8_e4m3 h(f); return (unsigned char)h.__x;
}
__device__ static inline float e4f(unsigned char b) {
  __hip_fp8_e4m3 h; h.__x = b; return (float)h;
}

__device__ static inline void load_lds16(const void* g, void* l) {
  __builtin_amdgcn_global_load_lds(
      (const __attribute__((address_space(1))) void*)g,
      (__attribute__((address_space(3))) void*)l, 16, 0, 0);
}

// ---------------- normalize: fp32 rows -> fp8 e4m3 normalized rows -----------
__global__ __launch_bounds__(256) void norm_kernel(
    const float* __restrict__ zi, const float* __restrict__ zj,
    unsigned char* __restrict__ ziN, unsigned char* __restrict__ zjN) {
  int rid = blockIdx.x * 4 + (threadIdx.x >> 6);   // 0..16383
  int lane = threadIdx.x & 63;
  const float* src;
  unsigned char* dst;
  if (rid < NROWS) { src = zi + (size_t)rid * DDIM; dst = ziN + (size_t)rid * DDIM; }
  else             { src = zj + (size_t)(rid - NROWS) * DDIM; dst = zjN + (size_t)(rid - NROWS) * DDIM; }
  float4 v0 = *(const float4*)(src + lane * 8);
  float4 v1 = *(const float4*)(src + lane * 8 + 4);
  float ss = v0.x*v0.x + v0.y*v0.y + v0.z*v0.z + v0.w*v0.w
           + v1.x*v1.x + v1.y*v1.y + v1.z*v1.z + v1.w*v1.w;
  #pragma unroll
  for (int off = 1; off < 64; off <<= 1) ss += __shfl_xor(ss, off);
  float scale = 1.0f / fmaxf(sqrtf(ss), 1e-8f);
  unsigned long long w = 0;
  w |= (unsigned long long)f2e4(v0.x * scale);
  w |= (unsigned long long)f2e4(v0.y * scale) << 8;
  w |= (unsigned long long)f2e4(v0.z * scale) << 16;
  w |= (unsigned long long)f2e4(v0.w * scale) << 24;
  w |= (unsigned long long)f2e4(v1.x * scale) << 32;
  w |= (unsigned long long)f2e4(v1.y * scale) << 40;
  w |= (unsigned long long)f2e4(v1.z * scale) << 48;
  w |= (unsigned long long)f2e4(v1.w * scale) << 56;
  *(unsigned long long*)(dst + lane * 8) = w;
}

// ---------------- zero row/col accumulators (contiguous 16384 floats) --------
__global__ __launch_bounds__(256) void zero_kernel(float* __restrict__ p) {
  p[blockIdx.x * 256 + threadIdx.x] = 0.0f;
}

// ---------------- pos[i] = dot(ziN[i], zjN[i]) / tau (fp8 inputs) ------------
__global__ __launch_bounds__(256) void pos_kernel(
    const unsigned char* __restrict__ ziN, const unsigned char* __restrict__ zjN,
    float* __restrict__ pos) {
  int row = blockIdx.x * 4 + (threadIdx.x >> 6);
  int lane = threadIdx.x & 63;
  unsigned long long a8 = *(const unsigned long long*)(ziN + (size_t)row * DDIM + lane * 8);
  unsigned long long b8 = *(const unsigned long long*)(zjN + (size_t)row * DDIM + lane * 8);
  float s = 0.0f;
  #pragma unroll
  for (int j = 0; j < 8; ++j)
    s += e4f((unsigned char)(a8 >> (8 * j))) * e4f((unsigned char)(b8 >> (8 * j)));
  #pragma unroll
  for (int off = 1; off < 64; off <<= 1) s += __shfl_xor(s, off);
  if (lane == 0) pos[row] = s * INV_TAU;
}

// ---------------- fused sim GEMM + exp + row/col sum (fp8, TLP) ---------------
// 128x128 tile, BK=64, 4 waves (2x2, 64x64 each), single-buffer LDS 16KB,
// plain __syncthreads 2-barrier loop.  fp8 rows = 64 B; 16B-slot swizzle
// slot16 = c16 ^ (row&3) on BOTH global source (gload_lds dest linear) and
// frag ds_read_b64 addresses.
__global__ __launch_bounds__(256, 4) void sim_fp8(
    const unsigned char* __restrict__ ziN, const unsigned char* __restrict__ zjN,
    float* __restrict__ row_sum, float* __restrict__ col_sum) {
  __shared__ __align__(16) unsigned char As[8192];   // 128 rows x 64 B
  __shared__ __align__(16) unsigned char Bs[8192];

  const int tid  = threadIdx.x;
  const int lane = tid & 63;
  const int wid  = tid >> 6;
  const int wr   = wid >> 1, wc = wid & 1;   // 2x2 waves, 64x64 each
  const int fr   = lane & 15;
  const int g    = lane >> 4;
  const int brow = blockIdx.y * 128;
  const int bcol = blockIdx.x * 128;

  f32x4 acc[4][4] = {};

  #pragma unroll 1
  for (int kt = 0; kt < 8; ++kt) {
    if (kt) __syncthreads();     // WAR: prior reads done before overwrite
    #pragma unroll
    for (int q = 0; q < 2; ++q) {
      int idx = q * 256 + tid;             // 0..511
      int row = idx >> 2;                  // 0..127
      int c16 = idx & 3;
      load_lds16(ziN + (size_t)(brow + row) * DDIM + kt * 64 + ((c16 ^ (row & 3)) << 4),
                 (char*)As + idx * 16);
    }
    #pragma unroll
    for (int q = 0; q < 2; ++q) {
      int idx = q * 256 + tid;
      int row = idx >> 2;
      int c16 = idx & 3;
      load_lds16(zjN + (size_t)(bcol + row) * DDIM + kt * 64 + ((c16 ^ (row & 3)) << 4),
                 (char*)Bs + idx * 16);
    }
    __syncthreads();             // RAW: staged data visible (vmcnt drain)
    #pragma unroll
    for (int kk = 0; kk < 2; ++kk) {
      long a[4], b[4];
      const int ch  = kk * 4 + g;          // 8B chunk index 0..7
      const int c16 = ch >> 1, h = ch & 1;
      #pragma unroll
      for (int m = 0; m < 4; ++m) {
        int row = wr * 64 + m * 16 + fr;
        a[m] = *(const long*)((const char*)As + row * 64 + ((c16 ^ (row & 3)) << 4) + h * 8);
      }
      #pragma unroll
      for (int n = 0; n < 4; ++n) {
        int row = wc * 64 + n * 16 + fr;
        b[n] = *(const long*)((const char*)Bs + row * 64 + ((c16 ^ (row & 3)) << 4) + h * 8);
      }
      #pragma unroll
      for (int m = 0; m < 4; ++m)
        #pragma unroll
        for (int n = 0; n < 4; ++n)
          acc[m][n] = __builtin_amdgcn_mfma_f32_16x16x32_fp8_fp8(a[m], b[n], acc[m][n], 0, 0, 0);
    }
  }

  // epilogue: e = exp2((dot-1)*C), diag -> 0, row/col partial sums + atomics
  const float Cc = INV_TAU * 1.4426950408889634f;
  const int r0 = brow + wr * 64 + g * 4;   // + m*16 + r
  const int c0 = bcol + wc * 64 + fr;      // + n*16
  #pragma unroll
  for (int m = 0; m < 4; ++m)
    #pragma unroll
    for (int n = 0; n < 4; ++n)
      #pragma unroll
      for (int r = 0; r < 4; ++r) {
        int gi = r0 + m * 16 + r;
        int gj = c0 + n * 16;
        float e = exp2f((acc[m][n][r] - 1.0f) * Cc);
        acc[m][n][r] = (gi == gj) ? 0.0f : e;
      }
  #pragma unroll
  for (int n = 0; n < 4; ++n) {
    float cs = 0.0f;
    #pragma unroll
    for (int m = 0; m < 4; ++m)
      #pragma unroll
      for (int r = 0; r < 4; ++r) cs += acc[m][n][r];
    cs += __shfl_xor(cs, 16);
    cs += __shfl_xor(cs, 32);
    if (lane < 16) atomicAdd(&col_sum[c0 + n * 16], cs);
  }
  #pragma unroll
  for (int m = 0; m < 4; ++m)
    #pragma unroll
    for (int r = 0; r < 4; ++r) {
      float rs = acc[m][0][r] + acc[m][1][r] + acc[m][2][r] + acc[m][3][r];
      rs += __shfl_xor(rs, 1);
      rs += __shfl_xor(rs, 2);
      rs += __shfl_xor(rs, 4);
      rs += __shfl_xor(rs, 8);
      if (fr == 0) atomicAdd(&row_sum[r0 + m * 16 + r], rs);
    }
}

// ---------------- finalize: 3 scalars ----------------------------------------
__global__ __launch_bounds__(256) void finalize_kernel(
    const float* __restrict__ row_sum, const float* __restrict__ col_sum,
    const float* __restrict__ pos, float* __restrict__ out) {
  __shared__ float sA[4], sB[4];
  float sa = 0.0f, sb = 0.0f;
  for (int i = threadIdx.x; i < NROWS; i += 256) {
    float p = pos[i];
    sa += (INV_TAU + __logf(row_sum[i])) - p;
    sb += (INV_TAU + __logf(col_sum[i])) - p;
  }
  #pragma unroll
  for (int off = 1; off < 64; off <<= 1) {
    sa += __shfl_xor(sa, off);
    sb += __shfl_xor(sb, off);
  }
  if ((threadIdx.x & 63) == 0) { sA[threadIdx.x >> 6] = sa; sB[threadIdx.x >> 6] = sb; }
  __syncthreads();
  if (threadIdx.x == 0) {
    float ta = sA[0] + sA[1] + sA[2] + sA[3];
    float tb = sB[0] + sB[1] + sB[2] + sB[3];
    float e2t = ta / (float)NROWS;
    float t2e = tb / (float)NROWS;
    out[0] = 0.5f * (e2t + t2e);
    out[1] = e2t;
    out[2] = t2e;
  }
}

extern "C" void kernel_launch(void* const* d_in, const int* in_sizes, int n_in,
                              void* d_out, int out_size, void* d_ws, size_t ws_size,
                              hipStream_t stream) {
  const float* z_i = (const float*)d_in[0];
  const float* z_j = (const float*)d_in[1];
  float* out = (float*)d_out;
  char* ws = (char*)d_ws;
  unsigned char* ziN = (unsigned char*)ws;                         // 4 MB
  unsigned char* zjN = (unsigned char*)(ws + 4194304);             // 4 MB
  float* row_sum = (float*)(ws + 8388608);                         // 32 KB
  float* col_sum = row_sum + NROWS;                                // 32 KB (contiguous)
  float* pos     = col_sum + NROWS;                                // 32 KB

  norm_kernel<<<4096, 256, 0, stream>>>(z_i, z_j, ziN, zjN);
  zero_kernel<<<64, 256, 0, stream>>>(row_sum);                    // zeros row+col (contiguous)
  pos_kernel<<<2048, 256, 0, stream>>>(ziN, zjN, pos);
  dim3 grid(64, 64);
  sim_fp8<<<grid, 256, 0, stream>>>(ziN, zjN, row_sum, col_sum);
  finalize_kernel<<<1, 256, 0, stream>>>(row_sum, col_sum, pos, out);
}